// Round 16
// baseline (132.483 us; speedup 1.0000x reference)
//
#include <hip/hip_runtime.h>
#include <hip/hip_bf16.h>
#include <math.h>

#define BB 2
#define TT 2048
#define DM 1024
#define NH 16
#define HS 64
#define MM (BB*TT)   // 4096

typedef __attribute__((ext_vector_type(8))) short s16x8;
typedef __attribute__((ext_vector_type(4))) float f32x4;

#define MFMA16(a,b,c) __builtin_amdgcn_mfma_f32_16x16x32_bf16((a),(b),(c),0,0,0)

__device__ inline unsigned short f2bf(float f) {   // RNE
    union { float f; unsigned u; } x; x.f = f;
    unsigned r = x.u + 0x7fff + ((x.u >> 16) & 1);
    return (unsigned short)(r >> 16);
}
__device__ inline unsigned short f2bfr(float f) {  // round-half-up (hot path)
    union { float f; unsigned u; } x; x.f = f;
    return (unsigned short)((x.u + 0x8000u) >> 16);
}

__device__ __forceinline__ void gload16(const void* g, void* l) {
    __builtin_amdgcn_global_load_lds(
        (const __attribute__((address_space(1))) unsigned int*)g,
        (__attribute__((address_space(3))) unsigned int*)l, 16, 0, 0);
}

// ---------------------------------------------------------------------------
// Kernel 0: weight convert+transpose, vectorized loads (unchanged).
// ---------------------------------------------------------------------------
__global__ __launch_bounds__(256) void cvt_w_kernel(
    const float* __restrict__ W0, const float* __restrict__ W1,
    const float* __restrict__ W2, unsigned short* __restrict__ dst, int wo_mode)
{
    __shared__ __align__(16) short Tt[64 * 72];
    const int t = threadIdx.x;
    const int d0 = blockIdx.x * 64;
    const int h  = blockIdx.y;
    const int z  = blockIdx.z;
    const float* W = (z == 0) ? W0 : (z == 1) ? W1 : W2;
    unsigned short* dz = dst + (size_t)z * DM * DM;

    const int hs4 = (t & 15) * 4;
    const int dl0 = t >> 4;
    #pragma unroll
    for (int it = 0; it < 4; ++it) {
        int dl = it * 16 + dl0;
        const float* src = wo_mode
            ? &W[(size_t)(d0 + dl) * DM + h * 64 + hs4]
            : &W[(size_t)h * DM * HS + (size_t)(d0 + dl) * HS + hs4];
        float4 vv = *(const float4*)src;
        Tt[(hs4 + 0) * 72 + dl] = (short)f2bf(vv.x);
        Tt[(hs4 + 1) * 72 + dl] = (short)f2bf(vv.y);
        Tt[(hs4 + 2) * 72 + dl] = (short)f2bf(vv.z);
        Tt[(hs4 + 3) * 72 + dl] = (short)f2bf(vv.w);
    }
    __syncthreads();
    int hs = t >> 2, doff = (t & 3) * 16;
    s16x8 r0 = *(s16x8*)&Tt[hs * 72 + doff];
    s16x8 r1 = *(s16x8*)&Tt[hs * 72 + doff + 8];
    unsigned short* op = dz + (size_t)(h * 64 + hs) * DM + d0 + doff;
    *(s16x8*)op = r0;
    *(s16x8*)(op + 8) = r1;
}

// ---------------------------------------------------------------------------
// Kernel 0b: x fp32 -> bf16 row-major, one streaming pass (fully coalesced).
// ---------------------------------------------------------------------------
__global__ __launch_bounds__(256) void cvt_x_kernel(
    const float* __restrict__ q, const float* __restrict__ k,
    const float* __restrict__ v, unsigned short* __restrict__ xb)
{
    const int z = blockIdx.z;
    const float* x = (z == 0) ? q : (z == 1) ? k : v;
    unsigned short* d = xb + (size_t)z * MM * DM;
    const size_t i = ((size_t)blockIdx.x * 256 + threadIdx.x) * 8;
    float4 a0 = *(const float4*)&x[i];
    float4 a1 = *(const float4*)&x[i + 4];
    union { s16x8 v; __hip_bfloat162 h[4]; } cv;
    cv.h[0] = __float22bfloat162_rn(make_float2(a0.x, a0.y));
    cv.h[1] = __float22bfloat162_rn(make_float2(a0.z, a0.w));
    cv.h[2] = __float22bfloat162_rn(make_float2(a1.x, a1.y));
    cv.h[3] = __float22bfloat162_rn(make_float2(a1.z, a1.w));
    *(s16x8*)&d[i] = cv.v;
}

// ---------------------------------------------------------------------------
// Kernel 1: Q/K/V projection GEMM — m97 replica. 256 thr / 4 waves (64x64
// each, acc[4][4]); BOTH operands bf16 via global_load_lds (2 chunks each);
// counted vmcnt(4) 2-barrier loop; consume = 8 ds_read_b128 + 16 MFMA.
// XCD m-panel ownership.
// ---------------------------------------------------------------------------
__global__ __launch_bounds__(256) void proj_gemm_kernel(
    const unsigned short* __restrict__ xb, const unsigned short* __restrict__ Wt,
    unsigned short* __restrict__ Qb, unsigned short* __restrict__ Kb,
    unsigned short* __restrict__ Vt)
{
    __shared__ __align__(16) unsigned short As[2][128 * 32];
    __shared__ __align__(16) unsigned short Bs[2][128 * 32];

    const int tid = threadIdx.x;
    const int l = tid & 63, w = tid >> 6;
    const int wr = w >> 1, wc = w & 1;
    const int g = l >> 4, r16 = l & 15;

    // bid -> (z, m-panel, n-panel): XCD owns m-panels {xcd*4..xcd*4+3} per z.
    const int bid = blockIdx.x;
    const int xcd = bid & 7, u = bid >> 3;
    const int z = u >> 5, vv = u & 31;
    const int n0 = (vv >> 2) * 128;
    const int m0 = (xcd * 4 + (vv & 3)) * 128;

    const unsigned short* Az = xb + (size_t)z * MM * DM;
    const unsigned short* Wz = Wt + (size_t)z * DM * DM;

    // staging: 512 chunks per operand in 2 passes (pre-swizzled source,
    // linear LDS dest)
    const unsigned short* aS[2]; const unsigned short* bS[2];
    int sDof[2];
    #pragma unroll
    for (int p = 0; p < 2; ++p) {
        int qid = p * 256 + tid;
        int row = qid >> 2, gl = qid & 3;
        int col = ((gl ^ ((row >> 1) & 3)) * 8);
        aS[p] = Az + (size_t)(m0 + row) * DM + col;
        bS[p] = Wz + (size_t)(n0 + row) * DM + col;
        sDof[p] = qid * 8;
    }

    // fragment LDS offsets (k0-invariant)
    int aoff[4], boff[4];
    #pragma unroll
    for (int i = 0; i < 4; ++i) {
        int row = wr * 64 + i * 16 + r16;
        aoff[i] = row * 32 + ((g ^ ((row >> 1) & 3)) * 8);
    }
    #pragma unroll
    for (int c = 0; c < 4; ++c) {
        int row = wc * 64 + c * 16 + r16;
        boff[c] = row * 32 + ((g ^ ((row >> 1) & 3)) * 8);
    }

    f32x4 acc[4][4];
    #pragma unroll
    for (int i = 0; i < 4; ++i)
        #pragma unroll
        for (int c = 0; c < 4; ++c)
            #pragma unroll
            for (int j = 0; j < 4; ++j) acc[i][c][j] = 0.0f;

    #define PSTAGE(buf, k0_) do {                                        \
        _Pragma("unroll")                                                \
        for (int p = 0; p < 2; ++p) {                                    \
            gload16(aS[p] + (k0_), &As[(buf)][sDof[p]]);                 \
            gload16(bS[p] + (k0_), &Bs[(buf)][sDof[p]]);                 \
        }                                                                \
    } while (0)

    #define PCOMPUTE(buf) do {                                           \
        s16x8 af[4], bf[4];                                              \
        _Pragma("unroll")                                                \
        for (int i = 0; i < 4; ++i) af[i] = *(const s16x8*)&As[(buf)][aoff[i]]; \
        _Pragma("unroll")                                                \
        for (int c = 0; c < 4; ++c) bf[c] = *(const s16x8*)&Bs[(buf)][boff[c]]; \
        _Pragma("unroll")                                                \
        for (int i = 0; i < 4; ++i)                                      \
            _Pragma("unroll")                                            \
            for (int c = 0; c < 4; ++c)                                  \
                acc[i][c] = MFMA16(af[i], bf[c], acc[i][c]);             \
    } while (0)

    PSTAGE(0, 0);
    for (int t = 0; t < 31; ++t) {
        PSTAGE((t + 1) & 1, (t + 1) * 32);
        // outstanding: tile t (4) + tile t+1 (4) -> retire exactly tile t
        asm volatile("s_waitcnt vmcnt(4)" ::: "memory");
        __builtin_amdgcn_sched_barrier(0);
        __builtin_amdgcn_s_barrier();
        PCOMPUTE(t & 1);
        __builtin_amdgcn_s_barrier();
    }
    asm volatile("s_waitcnt vmcnt(0)" ::: "memory");
    __builtin_amdgcn_sched_barrier(0);
    __builtin_amdgcn_s_barrier();
    PCOMPUTE(1);
    #undef PSTAGE
    #undef PCOMPUTE

    const int h = (n0 >> 6) + wc;
    if (z != 2) {
        unsigned short* dst = (z == 0) ? Qb : Kb;
        const float sc = (z == 0) ? 0.18033688011112042f : 1.0f;  // 0.125*log2e
        #pragma unroll
        for (int i = 0; i < 4; ++i)
            #pragma unroll
            for (int j = 0; j < 4; ++j) {
                int row = m0 + wr * 64 + i * 16 + g * 4 + j;
                int bb = row >> 11, tt = row & (TT - 1);
                size_t rb = (((size_t)(bb * NH + h)) * TT + tt) * HS;
                #pragma unroll
                for (int c = 0; c < 4; ++c)
                    dst[rb + c * 16 + r16] = f2bf(acc[i][c][j] * sc);
            }
    } else {
        #pragma unroll
        for (int i = 0; i < 4; ++i) {
            int row0 = m0 + wr * 64 + i * 16 + g * 4;
            int bb = row0 >> 11, tt0 = row0 & (TT - 1);
            #pragma unroll
            for (int c = 0; c < 4; ++c) {
                int hs = c * 16 + r16;
                union { unsigned long long u; unsigned short s[4]; } pk;
                #pragma unroll
                for (int j = 0; j < 4; ++j) pk.s[j] = f2bf(acc[i][c][j]);
                *(unsigned long long*)&Vt[(((size_t)(bb * NH + h)) * HS + hs) * TT + tt0] = pk.u;
            }
        }
    }
}

// ---------------------------------------------------------------------------
// Kernel 3: out = Ob @ Wo + bo (fp32 out). 8-wave (unchanged).
// ---------------------------------------------------------------------------
__global__ __launch_bounds__(512) void out_gemm_kernel(
    const unsigned short* __restrict__ Ob, const unsigned short* __restrict__ Wot,
    const float* __restrict__ bo, float* __restrict__ out)
{
    __shared__ __align__(16) unsigned short As2[2][128 * 32];
    __shared__ __align__(16) unsigned short Bs2[2][128 * 32];

    const int tid = threadIdx.x;
    const int l = tid & 63, w = tid >> 6;
    const int wr = w >> 2, wc = w & 3;
    const int g = l >> 4, r16 = l & 15;

    const int bid = blockIdx.x;
    const int xcd = bid & 7, u = bid >> 3;
    const int n0 = (u >> 2) * 128;
    const int m0 = (xcd * 4 + (u & 3)) * 128;

    const int srow = tid >> 2, sgl = tid & 3;
    const int scol = ((sgl ^ ((srow >> 1) & 3)) * 8);
    const unsigned short* aS = Ob + (size_t)(m0 + srow) * DM + scol;
    const unsigned short* bS = Wot + (size_t)(n0 + srow) * DM + scol;
    const int sDof = tid * 8;

    int aoff[4], boff[2];
    #pragma unroll
    for (int i = 0; i < 4; ++i) {
        int row = wr * 64 + i * 16 + r16;
        aoff[i] = row * 32 + ((g ^ ((row >> 1) & 3)) * 8);
    }
    #pragma unroll
    for (int c = 0; c < 2; ++c) {
        int row = wc * 32 + c * 16 + r16;
        boff[c] = row * 32 + ((g ^ ((row >> 1) & 3)) * 8);
    }

    f32x4 acc[4][2];
    #pragma unroll
    for (int i = 0; i < 4; ++i)
        #pragma unroll
        for (int c = 0; c < 2; ++c)
            #pragma unroll
            for (int j = 0; j < 4; ++j) acc[i][c][j] = 0.0f;

    #define OSTAGE(buf, k0_) do {                                        \
        gload16(aS + (k0_), &As2[(buf)][sDof]);                          \
        gload16(bS + (k0_), &Bs2[(buf)][sDof]);                          \
    } while (0)

    #define OCOMPUTE(buf) do {                                           \
        s16x8 af[4], bf[2];                                              \
        _Pragma("unroll")                                                \
        for (int i = 0; i < 4; ++i) af[i] = *(const s16x8*)&As2[(buf)][aoff[i]]; \
        _Pragma("unroll")                                                \
        for (int c = 0; c < 2; ++c) bf[c] = *(const s16x8*)&Bs2[(buf)][boff[c]]; \
        _Pragma("unroll")                                                \
        for (int i = 0; i < 4; ++i)                                      \
            _Pragma("unroll")                                            \
            for (int c = 0; c < 2; ++c)                                  \
                acc[i][c] = MFMA16(af[i], bf[c], acc[i][c]);             \
    } while (0)

    OSTAGE(0, 0);
    for (int t = 0; t < 31; ++t) {
        OSTAGE((t + 1) & 1, (t + 1) * 32);
        asm volatile("s_waitcnt vmcnt(2)" ::: "memory");
        __builtin_amdgcn_sched_barrier(0);
        __builtin_amdgcn_s_barrier();
        OCOMPUTE(t & 1);
        __builtin_amdgcn_s_barrier();
    }
    asm volatile("s_waitcnt vmcnt(0)" ::: "memory");
    __builtin_amdgcn_sched_barrier(0);
    __builtin_amdgcn_s_barrier();
    OCOMPUTE(1);
    #undef OSTAGE
    #undef OCOMPUTE

    #pragma unroll
    for (int i = 0; i < 4; ++i)
        #pragma unroll
        for (int j = 0; j < 4; ++j) {
            int row = m0 + wr * 64 + i * 16 + g * 4 + j;
            #pragma unroll
            for (int c = 0; c < 2; ++c) {
                int col = n0 + wc * 32 + c * 16 + r16;
                out[(size_t)row * DM + col] = acc[i][c][j] + bo[col];
            }
        }
}

// ---------------------------------------------------------------------------
// Kernel 2: causal flash attention v8 (unchanged from round 15).
// ---------------------------------------------------------------------------
template<bool MASKED>
__device__ __forceinline__ void ftile7(
    int kv0, int t0, int r16, int g,
    const unsigned short* __restrict__ Kl,
    const unsigned short* __restrict__ Vl,
    short* __restrict__ Pw,
    const s16x8 (&qf)[2],
    float& l_run, f32x4 (&o)[4])
{
    const int rs = r16 & 7;
    float pe[4][4];
    #pragma unroll
    for (int c = 0; c < 4; ++c) {
        if (!MASKED || (kv0 + c * 16 <= t0 + 15)) {
            f32x4 s0;
            #pragma unroll
            for (int j = 0; j < 4; ++j) s0[j] = 0.0f;
            const int base = (c * 16 + r16) * 64;
            s16x8 kf0 = *(const s16x8*)&Kl[base + ((g ^ rs) * 8)];
            s16x8 kf1 = *(const s16x8*)&Kl[base + (((4 + g) ^ rs) * 8)];
            s0 = MFMA16(kf0, qf[0], s0);      // S^T[kv][q]
            s0 = MFMA16(kf1, qf[1], s0);
            #pragma unroll
            for (int j = 0; j < 4; ++j) {
                float e = __builtin_amdgcn_exp2f(s0[j] - 16.0f);
                if (MASKED)
                    e = (kv0 + c * 16 + g * 4 + j <= t0 + r16) ? e : 0.0f;
                pe[c][j] = e;
                l_run += e;
            }
        } else {
            #pragma unroll
            for (int j = 0; j < 4; ++j) pe[c][j] = 0.0f;
        }
    }

    #pragma unroll
    for (int c = 0; c < 2; ++c) {
        union { unsigned long long u; unsigned short s[4]; } pk;
        #pragma unroll
        for (int j = 0; j < 4; ++j) pk.s[j] = f2bfr(pe[c][j]);
        *(unsigned long long*)&Pw[r16 * 36 + c * 16 + g * 4] = pk.u;
    }
    {
        s16x8 pb = *(const s16x8*)&Pw[r16 * 36 + g * 8];
        #pragma unroll
        for (int c = 0; c < 4; ++c) {
            s16x8 vf = *(const s16x8*)&Vl[(c * 16 + r16) * 64 + ((g ^ rs) * 8)];
            o[c] = MFMA16(vf, pb, o[c]);      // O^T[hs][q]
        }
    }
    if (!MASKED || (kv0 + 32 <= t0 + 15)) {
        #pragma unroll
        for (int c = 0; c < 2; ++c) {
            union { unsigned long long u; unsigned short s[4]; } pk;
            #pragma unroll
            for (int j = 0; j < 4; ++j) pk.s[j] = f2bfr(pe[2 + c][j]);
            *(unsigned long long*)&Pw[r16 * 36 + c * 16 + g * 4] = pk.u;
        }
        s16x8 pb = *(const s16x8*)&Pw[r16 * 36 + g * 8];
        #pragma unroll
        for (int c = 0; c < 4; ++c) {
            s16x8 vf = *(const s16x8*)&Vl[(c * 16 + r16) * 64 + (((4 + g) ^ rs) * 8)];
            o[c] = MFMA16(vf, pb, o[c]);
        }
    }
}

__global__ __launch_bounds__(512) void flash8_kernel(
    const unsigned short* __restrict__ Qb,
    const unsigned short* __restrict__ Kb,
    const unsigned short* __restrict__ Vt,
    unsigned short* __restrict__ Ob)
{
    __shared__ __align__(16) unsigned short Kls[2][4096];
    __shared__ __align__(16) unsigned short Vls[2][4096];
    __shared__ __align__(16) short Pl[8][576];

    const int tid = threadIdx.x;
    const int l = tid & 63, w = tid >> 6;
    const int r16 = l & 15, g = l >> 4;

    const int bid = blockIdx.x;
    const int bh = bid & 31;
    const int jj = bid >> 5;
    const int qc = (jj < 8) ? (15 - jj) : (jj - 8);
    const int numt = 2 * qc + 2;
    const int b = bh >> 4, h = bh & 15;

    const unsigned short* Qp = Qb + (size_t)bh * TT * HS;
    const unsigned short* Kp = Kb + (size_t)bh * TT * HS;
    const unsigned short* Vp = Vt + (size_t)bh * HS * TT;
    unsigned short* Op = Ob + (size_t)b * TT * DM + h * HS;
    short* Pw = Pl[w];

    const int t0 = qc * 128 + w * 16;

    const int srow = tid >> 3, c8 = tid & 7;
    const unsigned short* kS = Kp + srow * HS + ((c8 ^ (srow & 7)) * 8);
    const unsigned short* vS = Vp + (size_t)srow * TT + ((c8 ^ (srow & 7)) * 8);
    const int d0 = tid * 8;

    s16x8 qf[2];
    #pragma unroll
    for (int s = 0; s < 2; ++s)
        qf[s] = *(const s16x8*)(Qp + (size_t)(t0 + r16) * HS + s * 32 + g * 8);

    float l_run = 0.0f;
    f32x4 o[4];
    #pragma unroll
    for (int c = 0; c < 4; ++c)
        #pragma unroll
        for (int j = 0; j < 4; ++j) o[c][j] = 0.0f;

    #define STAGE(buf, kv0_) do {                                   \
        gload16(kS + (size_t)(kv0_) * HS, &Kls[(buf)][d0]);         \
        gload16(vS + (kv0_), &Vls[(buf)][d0]);                      \
    } while (0)

    #define FTILE(kv0_, buf_) do {                                  \
        if ((kv0_) + 64 <= t0 + 1)                                  \
            ftile7<false>((kv0_), t0, r16, g, &Kls[(buf_)][0],      \
                          &Vls[(buf_)][0], Pw, qf, l_run, o);       \
        else if ((kv0_) <= t0 + 15)                                 \
            ftile7<true>((kv0_), t0, r16, g, &Kls[(buf_)][0],       \
                         &Vls[(buf_)][0], Pw, qf, l_run, o);        \
    } while (0)

    STAGE(0, 0);
    for (int t = 0; t < numt - 1; ++t) {
        STAGE((t + 1) & 1, (t + 1) * 64);
        asm volatile("s_waitcnt vmcnt(2)" ::: "memory");
        __builtin_amdgcn_sched_barrier(0);
        __builtin_amdgcn_s_barrier();
        FTILE(t * 64, t & 1);
        __builtin_amdgcn_s_barrier();
    }
    asm volatile("s_waitcnt vmcnt(0)" ::: "memory");
    __builtin_amdgcn_sched_barrier(0);
    __builtin_amdgcn_s_barrier();
    FTILE((numt - 1) * 64, (numt - 1) & 1);
    #undef STAGE
    #undef FTILE

    float ls = l_run;
    ls += __shfl_xor(ls, 16);
    ls += __shfl_xor(ls, 32);
    const float inv = 1.0f / ls;
    unsigned short* rp = Op + (size_t)(t0 + r16) * DM;
    #pragma unroll
    for (int c = 0; c < 4; ++c) {
        union { unsigned long long u; unsigned short s[4]; } pk;
        #pragma unroll
        for (int j = 0; j < 4; ++j) pk.s[j] = f2bfr(o[c][j] * inv);
        *(unsigned long long*)&rp[c * 16 + g * 4] = pk.u;
    }
}

// ---------------------------------------------------------------------------
extern "C" void kernel_launch(void* const* d_in, const int* in_sizes, int n_in,
                              void* d_out, int out_size, void* d_ws, size_t ws_size,
                              hipStream_t stream) {
    const float* q  = (const float*)d_in[0];
    const float* k  = (const float*)d_in[1];
    const float* v  = (const float*)d_in[2];
    const float* Wq = (const float*)d_in[3];
    const float* Wk = (const float*)d_in[4];
    const float* Wv = (const float*)d_in[5];
    const float* Wo = (const float*)d_in[6];
    const float* bo = (const float*)d_in[7];
    float* out = (float*)d_out;

    const size_t QKV_ELEMS = (size_t)BB * NH * TT * HS;  // 4 Mi elems (8 MB)
    unsigned short* Qb = (unsigned short*)d_ws;
    unsigned short* Kb = Qb + QKV_ELEMS;
    unsigned short* Vt = Kb + QKV_ELEMS;                 // [B,H,HS,T]
    unsigned short* R4 = Vt + QKV_ELEMS;                 // 8 MB shared region
    unsigned short* Wt = R4;                             // Wq/k/v^T (6 MB), pre-flash
    unsigned short* Ob = R4;                             // flash out, overwrites Wt
    unsigned short* Wot = Qb;                            // Wo^T (2 MB), post-flash
    unsigned short* xb = R4 + QKV_ELEMS;                 // x bf16 (24 MB @ 32MB off;
                                                         // ws>=56MB proven round 14)

    cvt_w_kernel<<<dim3(16, 16, 3), 256, 0, stream>>>(Wq, Wk, Wv, Wt, 0);
    cvt_x_kernel<<<dim3(2048, 1, 3), 256, 0, stream>>>(q, k, v, xb);
    proj_gemm_kernel<<<dim3(768), 256, 0, stream>>>(xb, Wt, Qb, Kb, Vt);
    flash8_kernel<<<dim3(512), 512, 0, stream>>>(Qb, Kb, Vt, Ob);
    cvt_w_kernel<<<dim3(16, 16, 1), 256, 0, stream>>>(Wo, Wo, Wo, Wot, 1);
    out_gemm_kernel<<<dim3(256), 512, 0, stream>>>(Ob, Wot, bo, out);
}

// Round 17
// 121.079 us; speedup vs baseline: 1.0942x; 1.0942x over previous
//
#include <hip/hip_runtime.h>
#include <hip/hip_bf16.h>
#include <math.h>

#define BB 2
#define TT 2048
#define DM 1024
#define NH 16
#define HS 64
#define MM (BB*TT)   // 4096

typedef __attribute__((ext_vector_type(8))) short s16x8;
typedef __attribute__((ext_vector_type(4))) float f32x4;

#define MFMA16(a,b,c) __builtin_amdgcn_mfma_f32_16x16x32_bf16((a),(b),(c),0,0,0)

__device__ inline unsigned short f2bf(float f) {   // RNE
    union { float f; unsigned u; } x; x.f = f;
    unsigned r = x.u + 0x7fff + ((x.u >> 16) & 1);
    return (unsigned short)(r >> 16);
}
__device__ inline unsigned short f2bfr(float f) {  // round-half-up (hot path)
    union { float f; unsigned u; } x; x.f = f;
    return (unsigned short)((x.u + 0x8000u) >> 16);
}

__device__ __forceinline__ void gload16(const void* g, void* l) {
    __builtin_amdgcn_global_load_lds(
        (const __attribute__((address_space(1))) unsigned int*)g,
        (__attribute__((address_space(3))) unsigned int*)l, 16, 0, 0);
}

// ---------------------------------------------------------------------------
// Kernel 0: weight convert+transpose, vectorized loads (round-15 version).
// ---------------------------------------------------------------------------
__global__ __launch_bounds__(256) void cvt_w_kernel(
    const float* __restrict__ W0, const float* __restrict__ W1,
    const float* __restrict__ W2, unsigned short* __restrict__ dst, int wo_mode)
{
    __shared__ __align__(16) short Tt[64 * 72];
    const int t = threadIdx.x;
    const int d0 = blockIdx.x * 64;
    const int h  = blockIdx.y;
    const int z  = blockIdx.z;
    const float* W = (z == 0) ? W0 : (z == 1) ? W1 : W2;
    unsigned short* dz = dst + (size_t)z * DM * DM;

    const int hs4 = (t & 15) * 4;
    const int dl0 = t >> 4;
    #pragma unroll
    for (int it = 0; it < 4; ++it) {
        int dl = it * 16 + dl0;
        const float* src = wo_mode
            ? &W[(size_t)(d0 + dl) * DM + h * 64 + hs4]
            : &W[(size_t)h * DM * HS + (size_t)(d0 + dl) * HS + hs4];
        float4 vv = *(const float4*)src;
        Tt[(hs4 + 0) * 72 + dl] = (short)f2bf(vv.x);
        Tt[(hs4 + 1) * 72 + dl] = (short)f2bf(vv.y);
        Tt[(hs4 + 2) * 72 + dl] = (short)f2bf(vv.z);
        Tt[(hs4 + 3) * 72 + dl] = (short)f2bf(vv.w);
    }
    __syncthreads();
    int hs = t >> 2, doff = (t & 3) * 16;
    s16x8 r0 = *(s16x8*)&Tt[hs * 72 + doff];
    s16x8 r1 = *(s16x8*)&Tt[hs * 72 + doff + 8];
    unsigned short* op = dz + (size_t)(h * 64 + hs) * DM + d0 + doff;
    *(s16x8*)op = r0;
    *(s16x8*)(op + 8) = r1;
}

// ---------------------------------------------------------------------------
// Kernel 1: Q/K/V projection GEMM (round-11/15 proven version).
// ---------------------------------------------------------------------------
__global__ __launch_bounds__(512) void proj_gemm_kernel(
    const float* __restrict__ q, const float* __restrict__ k,
    const float* __restrict__ v, const unsigned short* __restrict__ Wt,
    unsigned short* __restrict__ Qb, unsigned short* __restrict__ Kb,
    unsigned short* __restrict__ Vt)
{
    __shared__ __align__(16) unsigned short As[2][128 * 32];
    __shared__ __align__(16) unsigned short Bs[2][128 * 32];

    const int tid = threadIdx.x;
    const int l = tid & 63, w = tid >> 6;
    const int wr = w >> 2, wc = w & 3;
    const int g = l >> 4, r16 = l & 15;

    const int bid = blockIdx.x;
    const int xcd = bid & 7, u = bid >> 3;
    const int z = u >> 5, vv = u & 31;
    const int n0 = (vv >> 2) * 128;
    const int m0 = (xcd * 4 + (vv & 3)) * 128;

    const float* x = (z == 0) ? q : (z == 1) ? k : v;
    const unsigned short* Wz = Wt + (size_t)z * DM * DM;

    const int ar = tid >> 2, aq = tid & 3;
    const float* axp = x + (size_t)(m0 + ar) * DM + aq * 8;
    const int axr = (ar >> 1) & 3;
    const int awof = ar * 32 + ((aq ^ axr) * 8);

    const int brow = tid >> 2, bgl = tid & 3;
    const unsigned short* bS = Wz + (size_t)(n0 + brow) * DM
                             + ((bgl ^ ((brow >> 1) & 3)) * 8);
    const int bDof = tid * 8;

    int aoff[4], boff[2];
    #pragma unroll
    for (int i = 0; i < 4; ++i) {
        int row = wr * 64 + i * 16 + r16;
        aoff[i] = row * 32 + ((g ^ ((row >> 1) & 3)) * 8);
    }
    #pragma unroll
    for (int c = 0; c < 2; ++c) {
        int row = wc * 32 + c * 16 + r16;
        boff[c] = row * 32 + ((g ^ ((row >> 1) & 3)) * 8);
    }

    f32x4 acc[4][2];
    #pragma unroll
    for (int i = 0; i < 4; ++i)
        #pragma unroll
        for (int c = 0; c < 2; ++c)
            #pragma unroll
            for (int j = 0; j < 4; ++j) acc[i][c][j] = 0.0f;

    float4 al0, al1;

    #define PLOADA(k0_) do {                                             \
        const float* ap = axp + (k0_);                                   \
        al0 = *(const float4*)(ap);                                      \
        al1 = *(const float4*)(ap + 4);                                  \
    } while (0)

    #define GLOADB(buf, k0_) gload16(bS + (k0_), &Bs[(buf)][bDof])

    #define PSTORE(buf) do {                                             \
        union { s16x8 v; __hip_bfloat162 h[4]; } c0;                     \
        c0.h[0] = __float22bfloat162_rn(make_float2(al0.x, al0.y));      \
        c0.h[1] = __float22bfloat162_rn(make_float2(al0.z, al0.w));      \
        c0.h[2] = __float22bfloat162_rn(make_float2(al1.x, al1.y));      \
        c0.h[3] = __float22bfloat162_rn(make_float2(al1.z, al1.w));      \
        *(s16x8*)&As[(buf)][awof] = c0.v;                                \
    } while (0)

    #define PCOMPUTE(buf) do {                                           \
        s16x8 af[4], bf[2];                                              \
        _Pragma("unroll")                                                \
        for (int i = 0; i < 4; ++i) af[i] = *(const s16x8*)&As[(buf)][aoff[i]]; \
        _Pragma("unroll")                                                \
        for (int c = 0; c < 2; ++c) bf[c] = *(const s16x8*)&Bs[(buf)][boff[c]]; \
        _Pragma("unroll")                                                \
        for (int i = 0; i < 4; ++i)                                      \
            _Pragma("unroll")                                            \
            for (int c = 0; c < 2; ++c)                                  \
                acc[i][c] = MFMA16(af[i], bf[c], acc[i][c]);             \
    } while (0)

    PLOADA(0);
    GLOADB(0, 0);
    PSTORE(0);
    for (int t = 0; t < 31; ++t) {
        const int cur = t & 1;
        PLOADA((t + 1) * 32);
        GLOADB(cur ^ 1, (t + 1) * 32);
        asm volatile("s_waitcnt vmcnt(3) lgkmcnt(0)" ::: "memory");
        __builtin_amdgcn_sched_barrier(0);
        __builtin_amdgcn_s_barrier();
        PCOMPUTE(cur);
        PSTORE(cur ^ 1);
        __builtin_amdgcn_s_barrier();
    }
    asm volatile("s_waitcnt vmcnt(0) lgkmcnt(0)" ::: "memory");
    __builtin_amdgcn_sched_barrier(0);
    __builtin_amdgcn_s_barrier();
    PCOMPUTE(1);
    #undef PLOADA
    #undef GLOADB
    #undef PSTORE
    #undef PCOMPUTE

    const int h = (n0 >> 6) + (wc >> 1);
    const int hsb = (wc & 1) * 32;
    if (z != 2) {
        unsigned short* dst = (z == 0) ? Qb : Kb;
        const float sc = (z == 0) ? 0.18033688011112042f : 1.0f;  // 0.125*log2e
        #pragma unroll
        for (int i = 0; i < 4; ++i)
            #pragma unroll
            for (int j = 0; j < 4; ++j) {
                int row = m0 + wr * 64 + i * 16 + g * 4 + j;
                int bb = row >> 11, tt = row & (TT - 1);
                size_t rb = (((size_t)(bb * NH + h)) * TT + tt) * HS;
                #pragma unroll
                for (int c = 0; c < 2; ++c)
                    dst[rb + hsb + c * 16 + r16] = f2bf(acc[i][c][j] * sc);
            }
    } else {
        #pragma unroll
        for (int i = 0; i < 4; ++i) {
            int row0 = m0 + wr * 64 + i * 16 + g * 4;
            int bb = row0 >> 11, tt0 = row0 & (TT - 1);
            #pragma unroll
            for (int c = 0; c < 2; ++c) {
                int hs = hsb + c * 16 + r16;
                union { unsigned long long u; unsigned short s[4]; } pk;
                #pragma unroll
                for (int j = 0; j < 4; ++j) pk.s[j] = f2bf(acc[i][c][j]);
                *(unsigned long long*)&Vt[(((size_t)(bb * NH + h)) * HS + hs) * TT + tt0] = pk.u;
            }
        }
    }
}

// ---------------------------------------------------------------------------
// Kernel 3: out = Ob @ Wo + bo (fp32 out). 8-wave (unchanged).
// ---------------------------------------------------------------------------
__global__ __launch_bounds__(512) void out_gemm_kernel(
    const unsigned short* __restrict__ Ob, const unsigned short* __restrict__ Wot,
    const float* __restrict__ bo, float* __restrict__ out)
{
    __shared__ __align__(16) unsigned short As2[2][128 * 32];
    __shared__ __align__(16) unsigned short Bs2[2][128 * 32];

    const int tid = threadIdx.x;
    const int l = tid & 63, w = tid >> 6;
    const int wr = w >> 2, wc = w & 3;
    const int g = l >> 4, r16 = l & 15;

    const int bid = blockIdx.x;
    const int xcd = bid & 7, u = bid >> 3;
    const int n0 = (u >> 2) * 128;
    const int m0 = (xcd * 4 + (u & 3)) * 128;

    const int srow = tid >> 2, sgl = tid & 3;
    const int scol = ((sgl ^ ((srow >> 1) & 3)) * 8);
    const unsigned short* aS = Ob + (size_t)(m0 + srow) * DM + scol;
    const unsigned short* bS = Wot + (size_t)(n0 + srow) * DM + scol;
    const int sDof = tid * 8;

    int aoff[4], boff[2];
    #pragma unroll
    for (int i = 0; i < 4; ++i) {
        int row = wr * 64 + i * 16 + r16;
        aoff[i] = row * 32 + ((g ^ ((row >> 1) & 3)) * 8);
    }
    #pragma unroll
    for (int c = 0; c < 2; ++c) {
        int row = wc * 32 + c * 16 + r16;
        boff[c] = row * 32 + ((g ^ ((row >> 1) & 3)) * 8);
    }

    f32x4 acc[4][2];
    #pragma unroll
    for (int i = 0; i < 4; ++i)
        #pragma unroll
        for (int c = 0; c < 2; ++c)
            #pragma unroll
            for (int j = 0; j < 4; ++j) acc[i][c][j] = 0.0f;

    #define OSTAGE(buf, k0_) do {                                        \
        gload16(aS + (k0_), &As2[(buf)][sDof]);                          \
        gload16(bS + (k0_), &Bs2[(buf)][sDof]);                          \
    } while (0)

    #define OCOMPUTE(buf) do {                                           \
        s16x8 af[4], bf[2];                                              \
        _Pragma("unroll")                                                \
        for (int i = 0; i < 4; ++i) af[i] = *(const s16x8*)&As2[(buf)][aoff[i]]; \
        _Pragma("unroll")                                                \
        for (int c = 0; c < 2; ++c) bf[c] = *(const s16x8*)&Bs2[(buf)][boff[c]]; \
        _Pragma("unroll")                                                \
        for (int i = 0; i < 4; ++i)                                      \
            _Pragma("unroll")                                            \
            for (int c = 0; c < 2; ++c)                                  \
                acc[i][c] = MFMA16(af[i], bf[c], acc[i][c]);             \
    } while (0)

    OSTAGE(0, 0);
    for (int t = 0; t < 31; ++t) {
        OSTAGE((t + 1) & 1, (t + 1) * 32);
        asm volatile("s_waitcnt vmcnt(2)" ::: "memory");
        __builtin_amdgcn_sched_barrier(0);
        __builtin_amdgcn_s_barrier();
        OCOMPUTE(t & 1);
        __builtin_amdgcn_s_barrier();
    }
    asm volatile("s_waitcnt vmcnt(0)" ::: "memory");
    __builtin_amdgcn_sched_barrier(0);
    __builtin_amdgcn_s_barrier();
    OCOMPUTE(1);
    #undef OSTAGE
    #undef OCOMPUTE

    #pragma unroll
    for (int i = 0; i < 4; ++i)
        #pragma unroll
        for (int j = 0; j < 4; ++j) {
            int row = m0 + wr * 64 + i * 16 + g * 4 + j;
            #pragma unroll
            for (int c = 0; c < 2; ++c) {
                int col = n0 + wc * 32 + c * 16 + r16;
                out[(size_t)row * DM + col] = acc[i][c][j] + bo[col];
            }
        }
}

// ---------------------------------------------------------------------------
// Kernel 2: causal flash attention v9 — flash8 + DUAL P buffers (break the
// half0/half1 LDS serialization) + s_setprio around MFMA clusters.
// ---------------------------------------------------------------------------
template<bool MASKED>
__device__ __forceinline__ void ftile9(
    int kv0, int t0, int r16, int g,
    const unsigned short* __restrict__ Kl,
    const unsigned short* __restrict__ Vl,
    short* __restrict__ Pw0, short* __restrict__ Pw1,
    const s16x8 (&qf)[2],
    float& l_run, f32x4 (&o)[4])
{
    const int rs = r16 & 7;
    const bool half1 = !MASKED || (kv0 + 32 <= t0 + 15);
    float pe[4][4];
    __builtin_amdgcn_s_setprio(1);
    f32x4 s0a[4];
    #pragma unroll
    for (int c = 0; c < 4; ++c) {
        if (!MASKED || (kv0 + c * 16 <= t0 + 15)) {
            f32x4 s0;
            #pragma unroll
            for (int j = 0; j < 4; ++j) s0[j] = 0.0f;
            const int base = (c * 16 + r16) * 64;
            s16x8 kf0 = *(const s16x8*)&Kl[base + ((g ^ rs) * 8)];
            s16x8 kf1 = *(const s16x8*)&Kl[base + (((4 + g) ^ rs) * 8)];
            s0 = MFMA16(kf0, qf[0], s0);      // S^T[kv][q]
            s0 = MFMA16(kf1, qf[1], s0);
            s0a[c] = s0;
        }
    }
    __builtin_amdgcn_s_setprio(0);
    #pragma unroll
    for (int c = 0; c < 4; ++c) {
        if (!MASKED || (kv0 + c * 16 <= t0 + 15)) {
            #pragma unroll
            for (int j = 0; j < 4; ++j) {
                float e = __builtin_amdgcn_exp2f(s0a[c][j] - 16.0f);
                if (MASKED)
                    e = (kv0 + c * 16 + g * 4 + j <= t0 + r16) ? e : 0.0f;
                pe[c][j] = e;
                l_run += e;
            }
        } else {
            #pragma unroll
            for (int j = 0; j < 4; ++j) pe[c][j] = 0.0f;
        }
    }

    // write BOTH halves to independent buffers, then read both
    #pragma unroll
    for (int c = 0; c < 2; ++c) {
        union { unsigned long long u; unsigned short s[4]; } pk;
        #pragma unroll
        for (int j = 0; j < 4; ++j) pk.s[j] = f2bfr(pe[c][j]);
        *(unsigned long long*)&Pw0[r16 * 36 + c * 16 + g * 4] = pk.u;
    }
    if (half1) {
        #pragma unroll
        for (int c = 0; c < 2; ++c) {
            union { unsigned long long u; unsigned short s[4]; } pk;
            #pragma unroll
            for (int j = 0; j < 4; ++j) pk.s[j] = f2bfr(pe[2 + c][j]);
            *(unsigned long long*)&Pw1[r16 * 36 + c * 16 + g * 4] = pk.u;
        }
    }
    s16x8 pb0 = *(const s16x8*)&Pw0[r16 * 36 + g * 8];
    __builtin_amdgcn_s_setprio(1);
    #pragma unroll
    for (int c = 0; c < 4; ++c) {
        s16x8 vf = *(const s16x8*)&Vl[(c * 16 + r16) * 64 + ((g ^ rs) * 8)];
        o[c] = MFMA16(vf, pb0, o[c]);         // O^T[hs][q]
    }
    if (half1) {
        s16x8 pb1 = *(const s16x8*)&Pw1[r16 * 36 + g * 8];
        #pragma unroll
        for (int c = 0; c < 4; ++c) {
            s16x8 vf = *(const s16x8*)&Vl[(c * 16 + r16) * 64 + (((4 + g) ^ rs) * 8)];
            o[c] = MFMA16(vf, pb1, o[c]);
        }
    }
    __builtin_amdgcn_s_setprio(0);
}

__global__ __launch_bounds__(512) void flash9_kernel(
    const unsigned short* __restrict__ Qb,
    const unsigned short* __restrict__ Kb,
    const unsigned short* __restrict__ Vt,
    unsigned short* __restrict__ Ob)
{
    __shared__ __align__(16) unsigned short Kls[2][4096];  // [64][64] x dbuf
    __shared__ __align__(16) unsigned short Vls[2][4096];
    __shared__ __align__(16) short Pl[8][2][576];          // per-wave dual P

    const int tid = threadIdx.x;
    const int l = tid & 63, w = tid >> 6;                  // 8 waves
    const int r16 = l & 15, g = l >> 4;

    const int bid = blockIdx.x;
    const int bh = bid & 31;
    const int jj = bid >> 5;
    const int qc = (jj < 8) ? (15 - jj) : (jj - 8);
    const int numt = 2 * qc + 2;
    const int b = bh >> 4, h = bh & 15;

    const unsigned short* Qp = Qb + (size_t)bh * TT * HS;
    const unsigned short* Kp = Kb + (size_t)bh * TT * HS;
    const unsigned short* Vp = Vt + (size_t)bh * HS * TT;
    unsigned short* Op = Ob + (size_t)b * TT * DM + h * HS;
    short* Pw0 = &Pl[w][0][0];
    short* Pw1 = &Pl[w][1][0];

    const int t0 = qc * 128 + w * 16;

    const int srow = tid >> 3, c8 = tid & 7;
    const unsigned short* kS = Kp + srow * HS + ((c8 ^ (srow & 7)) * 8);
    const unsigned short* vS = Vp + (size_t)srow * TT + ((c8 ^ (srow & 7)) * 8);
    const int d0 = tid * 8;

    s16x8 qf[2];
    #pragma unroll
    for (int s = 0; s < 2; ++s)
        qf[s] = *(const s16x8*)(Qp + (size_t)(t0 + r16) * HS + s * 32 + g * 8);

    float l_run = 0.0f;
    f32x4 o[4];
    #pragma unroll
    for (int c = 0; c < 4; ++c)
        #pragma unroll
        for (int j = 0; j < 4; ++j) o[c][j] = 0.0f;

    #define STAGE(buf, kv0_) do {                                   \
        gload16(kS + (size_t)(kv0_) * HS, &Kls[(buf)][d0]);         \
        gload16(vS + (kv0_), &Vls[(buf)][d0]);                      \
    } while (0)

    #define FTILE(kv0_, buf_) do {                                  \
        if ((kv0_) + 64 <= t0 + 1)                                  \
            ftile9<false>((kv0_), t0, r16, g, &Kls[(buf_)][0],      \
                          &Vls[(buf_)][0], Pw0, Pw1, qf, l_run, o); \
        else if ((kv0_) <= t0 + 15)                                 \
            ftile9<true>((kv0_), t0, r16, g, &Kls[(buf_)][0],       \
                         &Vls[(buf_)][0], Pw0, Pw1, qf, l_run, o);  \
    } while (0)

    STAGE(0, 0);
    for (int t = 0; t < numt - 1; ++t) {
        STAGE((t + 1) & 1, (t + 1) * 64);
        asm volatile("s_waitcnt vmcnt(2)" ::: "memory");   // retire tile t's pair
        __builtin_amdgcn_sched_barrier(0);
        __builtin_amdgcn_s_barrier();
        FTILE(t * 64, t & 1);
        __builtin_amdgcn_s_barrier();
    }
    asm volatile("s_waitcnt vmcnt(0)" ::: "memory");
    __builtin_amdgcn_sched_barrier(0);
    __builtin_amdgcn_s_barrier();
    FTILE((numt - 1) * 64, (numt - 1) & 1);
    #undef STAGE
    #undef FTILE

    float ls = l_run;
    ls += __shfl_xor(ls, 16);
    ls += __shfl_xor(ls, 32);
    const float inv = 1.0f / ls;
    unsigned short* rp = Op + (size_t)(t0 + r16) * DM;
    #pragma unroll
    for (int c = 0; c < 4; ++c) {
        union { unsigned long long u; unsigned short s[4]; } pk;
        #pragma unroll
        for (int j = 0; j < 4; ++j) pk.s[j] = f2bfr(o[c][j] * inv);
        *(unsigned long long*)&rp[c * 16 + g * 4] = pk.u;
    }
}

// ---------------------------------------------------------------------------
extern "C" void kernel_launch(void* const* d_in, const int* in_sizes, int n_in,
                              void* d_out, int out_size, void* d_ws, size_t ws_size,
                              hipStream_t stream) {
    const float* q  = (const float*)d_in[0];
    const float* k  = (const float*)d_in[1];
    const float* v  = (const float*)d_in[2];
    const float* Wq = (const float*)d_in[3];
    const float* Wk = (const float*)d_in[4];
    const float* Wv = (const float*)d_in[5];
    const float* Wo = (const float*)d_in[6];
    const float* bo = (const float*)d_in[7];
    float* out = (float*)d_out;

    const size_t QKV_ELEMS = (size_t)BB * NH * TT * HS;  // 4 Mi elems (8 MB)
    unsigned short* Qb = (unsigned short*)d_ws;
    unsigned short* Kb = Qb + QKV_ELEMS;
    unsigned short* Vt = Kb + QKV_ELEMS;                 // [B,H,HS,T]
    unsigned short* R4 = Vt + QKV_ELEMS;                 // 8 MB shared region
    unsigned short* Wt = R4;                             // Wq/k/v^T (6 MB), pre-flash
    unsigned short* Ob = R4;                             // flash out, overwrites Wt
    unsigned short* Wot = Qb;                            // Wo^T (2 MB), post-flash

    cvt_w_kernel<<<dim3(16, 16, 3), 256, 0, stream>>>(Wq, Wk, Wv, Wt, 0);
    proj_gemm_kernel<<<dim3(768), 512, 0, stream>>>(q, k, v, Wt, Qb, Kb, Vt);
    flash9_kernel<<<dim3(512), 512, 0, stream>>>(Qb, Kb, Vt, Ob);
    cvt_w_kernel<<<dim3(16, 16, 1), 256, 0, stream>>>(Wo, Wo, Wo, Wot, 1);
    out_gemm_kernel<<<dim3(256), 512, 0, stream>>>(Ob, Wot, bo, out);
}